// Round 5
// baseline (191.246 us; speedup 1.0000x reference)
//
#include <hip/hip_runtime.h>
#include <hip/hip_bf16.h>

#define B_  2
#define S_  512
#define H_  8
#define D_  32
#define DM_ 256
#define HD_ 256
#define NROW 4
#define TI  8          // i-rows per attention block
#define HC  2          // heads per attention block
#define NR  (TI * HC)  // 16 p-rows per block
#define PSTR 520       // padded p-row stride (8-bank rotation per row)

// ---------------------------------------------------------------------------
// Kernel A: QKV projection.  grid = (B*S/NROW, 3), block = 256.
// out layout: (b, h, s, d)
// ---------------------------------------------------------------------------
__global__ __launch_bounds__(256) void qkv_kernel(
    const float* __restrict__ hid, const float* __restrict__ wq,
    const float* __restrict__ wk, const float* __restrict__ wv,
    float* __restrict__ qo, float* __restrict__ ko, float* __restrict__ vo)
{
  __shared__ float hs[NROW][DM_];
  const int r0 = blockIdx.x * NROW;                 // global row in [0, B*S)
  const float* w   = (blockIdx.y == 0) ? wq : (blockIdx.y == 1) ? wk : wv;
  float*       out = (blockIdx.y == 0) ? qo : (blockIdx.y == 1) ? ko : vo;
  const int tid = threadIdx.x;

  for (int idx = tid; idx < NROW * DM_; idx += 256)
    hs[idx >> 8][idx & 255] = hid[r0 * DM_ + idx];
  __syncthreads();

  float acc[NROW] = {0.f, 0.f, 0.f, 0.f};
  const float* wp = w + tid;                        // column m = tid
  #pragma unroll 8
  for (int c4 = 0; c4 < DM_ / 4; ++c4) {
    const float w0 = wp[(4 * c4 + 0) * HD_];
    const float w1 = wp[(4 * c4 + 1) * HD_];
    const float w2 = wp[(4 * c4 + 2) * HD_];
    const float w3 = wp[(4 * c4 + 3) * HD_];
    #pragma unroll
    for (int r = 0; r < NROW; ++r) {
      const float4 hv = reinterpret_cast<const float4*>(&hs[r][0])[c4];
      acc[r] = fmaf(hv.x, w0, acc[r]);
      acc[r] = fmaf(hv.y, w1, acc[r]);
      acc[r] = fmaf(hv.z, w2, acc[r]);
      acc[r] = fmaf(hv.w, w3, acc[r]);
    }
  }
  const int h = tid >> 5, d = tid & 31;
  #pragma unroll
  for (int r = 0; r < NROW; ++r) {
    const int g = r0 + r;
    const int b = g >> 9, s = g & (S_ - 1);
    out[((b * H_ + h) * S_ + s) * D_ + d] = acc[r];
  }
}

// ---------------------------------------------------------------------------
// Kernel B: scores + mask + softmax + attn@V.
// 1-D grid of 512 blocks (XCD swizzle), block = 256 threads (4 waves).
// Block handles (b, 8 i-rows, 2 heads).  Each thread owns columns
// j = tid and j = tid+256, so ALL waves work during the score phase.
// K is read via wave-uniform global loads (-> scalar loads, no LDS stage).
// scores[b,h,i,j] = sum_d q[b,h,j,d] * k[b,h,i,d] * rpe[b,i,j,d] / sqrt(D)
// mask: j < station  OR  j == i.  p-row index r = hh*TI + ii.
// ---------------------------------------------------------------------------
__global__ __launch_bounds__(256, 3) void attn_kernel(
    const float* __restrict__ rpe, const float* __restrict__ q_ws,
    const float* __restrict__ k_ws, const float* __restrict__ v_ws,
    const int* __restrict__ station_p, float* __restrict__ o_ws)
{
  __shared__ float p_lds[NR][PSTR];     // 33.3 KB
  __shared__ float sums[NR];
  __shared__ float4 redv[4][NR][8];     // 8 KB

  const int tid = threadIdx.x;
  const int n   = blockIdx.x;                       // 0..511
  const int hg  = (n >> 3) & 3;
  const int t   = (n & 7) | ((n >> 5) << 3);        // 0..127 tile id
  const int b   = t >> 6;
  const int i0  = (t & 63) * TI;
  const int h0  = hg * HC;

  int station = station_p[0];
  station = station > S_ ? S_ : (station < 0 ? 0 : station);

  // wave-uniform K base pointers (addresses depend only on blockIdx)
  const float* kb0 = k_ws + ((b * H_ + h0) * S_ + i0) * D_;
  const float* kb1 = kb0 + S_ * D_;

  // ---- score phase: two column sets, no internal barriers ----
  #pragma unroll 1
  for (int half = 0; half < 2; ++half) {
    const int j  = tid + half * 256;
    const int dt = j - i0;
    const bool diag = ((unsigned)dt < (unsigned)TI);
    if ((j < station) || diag) {
      float a0[TI], a1[TI];
      #pragma unroll
      for (int ii = 0; ii < TI; ++ii) { a0[ii] = 0.f; a1[ii] = 0.f; }
      const float* qp0 = q_ws + ((b * H_ + h0) * S_ + j) * D_;
      const float* qp1 = qp0 + S_ * D_;
      const float* rp  = rpe + (((size_t)b * S_ + i0) * S_ + j) * D_;
      #pragma unroll
      for (int tt = 0; tt < 8; ++tt) {
        const float4 q0 = *reinterpret_cast<const float4*>(qp0 + tt * 4);
        const float4 q1 = *reinterpret_cast<const float4*>(qp1 + tt * 4);
        #pragma unroll
        for (int ii = 0; ii < TI; ++ii) {
          const float4 rv = *reinterpret_cast<const float4*>(rp + ii * (S_ * D_) + tt * 4);
          const float4 k0 = *reinterpret_cast<const float4*>(kb0 + ii * D_ + tt * 4);
          const float4 k1 = *reinterpret_cast<const float4*>(kb1 + ii * D_ + tt * 4);
          a0[ii] = fmaf(q0.x * k0.x, rv.x, a0[ii]);
          a0[ii] = fmaf(q0.y * k0.y, rv.y, a0[ii]);
          a0[ii] = fmaf(q0.z * k0.z, rv.z, a0[ii]);
          a0[ii] = fmaf(q0.w * k0.w, rv.w, a0[ii]);
          a1[ii] = fmaf(q1.x * k1.x, rv.x, a1[ii]);
          a1[ii] = fmaf(q1.y * k1.y, rv.y, a1[ii]);
          a1[ii] = fmaf(q1.z * k1.z, rv.z, a1[ii]);
          a1[ii] = fmaf(q1.w * k1.w, rv.w, a1[ii]);
        }
      }
      const float sc = 0.17677669529663687f;   // 1/sqrt(32)
      if (j < station) {
        #pragma unroll
        for (int ii = 0; ii < TI; ++ii) {
          p_lds[ii][j]      = a0[ii] * sc;
          p_lds[TI + ii][j] = a1[ii] * sc;
        }
      } else {
        #pragma unroll
        for (int ii = 0; ii < TI; ++ii) {
          if (dt == ii) {
            p_lds[ii][j]      = a0[ii] * sc;
            p_lds[TI + ii][j] = a1[ii] * sc;
          }
        }
      }
    }
  }
  __syncthreads();

  // ---- softmax: 4 waves, wave w -> rows [4w, 4w+4) ----
  {
    const int w = tid >> 6, lane = tid & 63;
    #pragma unroll
    for (int k = 0; k < 4; ++k) {
      const int r  = w * 4 + k;
      const int ii = r & 7;
      const int ig = i0 + ii;
      const bool dx = (ig >= station);
      float m = -1e30f;
      for (int jj = lane; jj < station; jj += 64) m = fmaxf(m, p_lds[r][jj]);
      const float dv = dx ? p_lds[r][ig] : -1e30f;   // uniform-addr broadcast
      m = fmaxf(m, dv);
      #pragma unroll
      for (int o = 32; o; o >>= 1) m = fmaxf(m, __shfl_xor(m, o, 64));
      float sum = 0.f;
      for (int jj = lane; jj < station; jj += 64) {
        const float e = __expf(p_lds[r][jj] - m);
        p_lds[r][jj] = e;
        sum += e;
      }
      #pragma unroll
      for (int o = 32; o; o >>= 1) sum += __shfl_xor(sum, o, 64);
      if (dx) {
        const float e = __expf(dv - m);
        sum += e;
        if (lane == 0) p_lds[r][ig] = e;
      }
      if (lane == 0) sums[r] = sum;
    }
  }
  __syncthreads();

  // ---- attn @ V: 4-way jj split (wave = part), lanes = (ii, d4), 2 heads ----
  {
    const int part = tid >> 6;          // 0..3 (wave id)
    const int lane = tid & 63;
    const int ii = lane >> 3, d4 = lane & 7;
    const float* v0 = v_ws + (size_t)((b * H_ + h0) * S_) * D_;
    const float* v1 = v0 + S_ * D_;
    float4 a0 = {0.f, 0.f, 0.f, 0.f};
    float4 a1 = {0.f, 0.f, 0.f, 0.f};
    #pragma unroll 4
    for (int jj = part; jj < station; jj += 4) {
      const float p0 = p_lds[ii][jj];
      const float p1 = p_lds[TI + ii][jj];
      const float4 vv0 = *reinterpret_cast<const float4*>(v0 + jj * D_ + d4 * 4);
      const float4 vv1 = *reinterpret_cast<const float4*>(v1 + jj * D_ + d4 * 4);
      a0.x = fmaf(p0, vv0.x, a0.x); a0.y = fmaf(p0, vv0.y, a0.y);
      a0.z = fmaf(p0, vv0.z, a0.z); a0.w = fmaf(p0, vv0.w, a0.w);
      a1.x = fmaf(p1, vv1.x, a1.x); a1.y = fmaf(p1, vv1.y, a1.y);
      a1.z = fmaf(p1, vv1.z, a1.z); a1.w = fmaf(p1, vv1.w, a1.w);
    }
    const int ig = i0 + ii;
    if (ig >= station && part == (ig & 3)) {
      const float p0 = p_lds[ii][ig];
      const float p1 = p_lds[TI + ii][ig];
      const float4 vv0 = *reinterpret_cast<const float4*>(v0 + ig * D_ + d4 * 4);
      const float4 vv1 = *reinterpret_cast<const float4*>(v1 + ig * D_ + d4 * 4);
      a0.x = fmaf(p0, vv0.x, a0.x); a0.y = fmaf(p0, vv0.y, a0.y);
      a0.z = fmaf(p0, vv0.z, a0.z); a0.w = fmaf(p0, vv0.w, a0.w);
      a1.x = fmaf(p1, vv1.x, a1.x); a1.y = fmaf(p1, vv1.y, a1.y);
      a1.z = fmaf(p1, vv1.z, a1.z); a1.w = fmaf(p1, vv1.w, a1.w);
    }
    redv[part][ii][d4] = a0;
    redv[part][TI + ii][d4] = a1;
  }
  __syncthreads();
  if (tid < NR * 8) {
    const int r = tid >> 3, d4 = tid & 7;
    float4 a = redv[0][r][d4];
    #pragma unroll
    for (int p = 1; p < 4; ++p) {
      const float4 x = redv[p][r][d4];
      a.x += x.x; a.y += x.y; a.z += x.z; a.w += x.w;
    }
    const float inv = 1.f / sums[r];
    a.x *= inv; a.y *= inv; a.z *= inv; a.w *= inv;
    const int hh = r >> 3, ii = r & 7;
    reinterpret_cast<float4*>(
        o_ws + ((b * H_ + h0 + hh) * S_ + i0 + ii) * D_)[d4] = a;
  }
}

// ---------------------------------------------------------------------------
// Kernel C: ctx = O @ fc_w + fc_b + hidden, then LayerNorm.
// grid = B*S/NROW, block = 256 (thread per output column m).
// ---------------------------------------------------------------------------
__global__ __launch_bounds__(256) void fc_ln_kernel(
    const float* __restrict__ o_ws, const float* __restrict__ fc_w,
    const float* __restrict__ fc_b, const float* __restrict__ hid,
    const float* __restrict__ ln_w, const float* __restrict__ ln_b,
    float* __restrict__ out)
{
  __shared__ float orow[NROW][HD_];
  __shared__ float red[NROW][4];
  const int tid = threadIdx.x;
  const int r0 = blockIdx.x * NROW;

  for (int idx = tid; idx < NROW * HD_; idx += 256) {
    const int r = idx >> 8, m = idx & 255;
    const int g = r0 + r;
    const int b = g >> 9, i = g & (S_ - 1);
    orow[r][m] = o_ws[((b * H_ + (m >> 5)) * S_ + i) * D_ + (m & 31)];
  }
  __syncthreads();

  float acc[NROW] = {0.f, 0.f, 0.f, 0.f};
  const float* wp = fc_w + tid;
  #pragma unroll 8
  for (int n4 = 0; n4 < HD_ / 4; ++n4) {
    const float w0 = wp[(4 * n4 + 0) * DM_];
    const float w1 = wp[(4 * n4 + 1) * DM_];
    const float w2 = wp[(4 * n4 + 2) * DM_];
    const float w3 = wp[(4 * n4 + 3) * DM_];
    #pragma unroll
    for (int r = 0; r < NROW; ++r) {
      const float4 ov = reinterpret_cast<const float4*>(&orow[r][0])[n4];
      acc[r] = fmaf(ov.x, w0, acc[r]);
      acc[r] = fmaf(ov.y, w1, acc[r]);
      acc[r] = fmaf(ov.z, w2, acc[r]);
      acc[r] = fmaf(ov.w, w3, acc[r]);
    }
  }
  const float bias = fc_b[tid];
  #pragma unroll
  for (int r = 0; r < NROW; ++r) acc[r] += bias + hid[(r0 + r) * DM_ + tid];

  // ---- LayerNorm over DM per row ----
  const int w = tid >> 6, lane = tid & 63;
  float mu[NROW];
  #pragma unroll
  for (int r = 0; r < NROW; ++r) {
    float s = acc[r];
    #pragma unroll
    for (int o = 32; o; o >>= 1) s += __shfl_xor(s, o, 64);
    if (lane == 0) red[r][w] = s;
  }
  __syncthreads();
  #pragma unroll
  for (int r = 0; r < NROW; ++r)
    mu[r] = (red[r][0] + red[r][1] + red[r][2] + red[r][3]) * (1.f / DM_);
  __syncthreads();
  #pragma unroll
  for (int r = 0; r < NROW; ++r) {
    const float dd = acc[r] - mu[r];
    float s = dd * dd;
    #pragma unroll
    for (int o = 32; o; o >>= 1) s += __shfl_xor(s, o, 64);
    if (lane == 0) red[r][w] = s;
  }
  __syncthreads();
  const float lw = ln_w[tid], lb = ln_b[tid];
  #pragma unroll
  for (int r = 0; r < NROW; ++r) {
    const float var = (red[r][0] + red[r][1] + red[r][2] + red[r][3]) * (1.f / DM_);
    out[(r0 + r) * DM_ + tid] =
        (acc[r] - mu[r]) * rsqrtf(var + 1e-6f) * lw + lb;
  }
}

// ---------------------------------------------------------------------------
extern "C" void kernel_launch(void* const* d_in, const int* in_sizes, int n_in,
                              void* d_out, int out_size, void* d_ws, size_t ws_size,
                              hipStream_t stream) {
  const float* hid = (const float*)d_in[0];
  const float* rpe = (const float*)d_in[1];
  const float* wq  = (const float*)d_in[2];
  const float* wk  = (const float*)d_in[3];
  const float* wv  = (const float*)d_in[4];
  const float* fcw = (const float*)d_in[5];
  const float* fcb = (const float*)d_in[6];
  const float* lnw = (const float*)d_in[7];
  const float* lnb = (const float*)d_in[8];
  const int* station = (const int*)d_in[9];
  float* out = (float*)d_out;

  const size_t per = (size_t)B_ * H_ * S_ * D_;   // 262144 floats
  float* q_ws = (float*)d_ws;
  float* k_ws = q_ws + per;
  float* v_ws = k_ws + per;
  float* o_ws = v_ws + per;

  dim3 gA(B_ * S_ / NROW, 3);
  qkv_kernel<<<gA, 256, 0, stream>>>(hid, wq, wk, wv, q_ws, k_ws, v_ws);
  attn_kernel<<<B_ * (S_ / TI) * (H_ / HC), 256, 0, stream>>>(
      rpe, q_ws, k_ws, v_ws, station, o_ws);
  fc_ln_kernel<<<B_ * S_ / NROW, 256, 0, stream>>>(o_ws, fcw, fcb, hid, lnw, lnb, out);
}

// Round 6
// 178.023 us; speedup vs baseline: 1.0743x; 1.0743x over previous
//
#include <hip/hip_runtime.h>
#include <hip/hip_bf16.h>

#define B_  2
#define S_  512
#define H_  8
#define D_  32
#define DM_ 256
#define HD_ 256
#define NROW 4
#define TI  8          // i-rows per attention block

// ---------------------------------------------------------------------------
// Kernel A: QKV projection.  grid = (B*S/NROW, 3), block = 256.
// out layout: (b, h, s, d)
// ---------------------------------------------------------------------------
__global__ __launch_bounds__(256) void qkv_kernel(
    const float* __restrict__ hid, const float* __restrict__ wq,
    const float* __restrict__ wk, const float* __restrict__ wv,
    float* __restrict__ qo, float* __restrict__ ko, float* __restrict__ vo)
{
  __shared__ float hs[NROW][DM_];
  const int r0 = blockIdx.x * NROW;                 // global row in [0, B*S)
  const float* w   = (blockIdx.y == 0) ? wq : (blockIdx.y == 1) ? wk : wv;
  float*       out = (blockIdx.y == 0) ? qo : (blockIdx.y == 1) ? ko : vo;
  const int tid = threadIdx.x;

  for (int idx = tid; idx < NROW * DM_; idx += 256)
    hs[idx >> 8][idx & 255] = hid[r0 * DM_ + idx];
  __syncthreads();

  float acc[NROW] = {0.f, 0.f, 0.f, 0.f};
  const float* wp = w + tid;                        // column m = tid
  #pragma unroll 8
  for (int c4 = 0; c4 < DM_ / 4; ++c4) {
    const float w0 = wp[(4 * c4 + 0) * HD_];
    const float w1 = wp[(4 * c4 + 1) * HD_];
    const float w2 = wp[(4 * c4 + 2) * HD_];
    const float w3 = wp[(4 * c4 + 3) * HD_];
    #pragma unroll
    for (int r = 0; r < NROW; ++r) {
      const float4 hv = reinterpret_cast<const float4*>(&hs[r][0])[c4];
      acc[r] = fmaf(hv.x, w0, acc[r]);
      acc[r] = fmaf(hv.y, w1, acc[r]);
      acc[r] = fmaf(hv.z, w2, acc[r]);
      acc[r] = fmaf(hv.w, w3, acc[r]);
    }
  }
  const int h = tid >> 5, d = tid & 31;
  #pragma unroll
  for (int r = 0; r < NROW; ++r) {
    const int g = r0 + r;
    const int b = g >> 9, s = g & (S_ - 1);
    out[((b * H_ + h) * S_ + s) * D_ + d] = acc[r];
  }
}

// 8-lane (dc-group) sum reduction on the VALU pipe via DPP.
// Valid result at lanes with (lane&7)==0.
__device__ __forceinline__ float red8(float x) {
  int i;
  i = __builtin_amdgcn_mov_dpp(__float_as_int(x), 0xB1, 0xf, 0xf, true); // quad_perm xor1
  x += __int_as_float(i);
  i = __builtin_amdgcn_mov_dpp(__float_as_int(x), 0x4E, 0xf, 0xf, true); // quad_perm xor2
  x += __int_as_float(i);
  i = __builtin_amdgcn_mov_dpp(__float_as_int(x), 0x124, 0xf, 0xf, true); // row_ror:4
  x += __int_as_float(i);
  return x;
}

// ---------------------------------------------------------------------------
// Kernel B: scores + mask + softmax + attn@V.  All hot global loads COALESCED.
// 1024 blocks (XCD swizzle: 8 head-blocks of one rpe tile -> same XCD),
// 256 threads (4 waves).  Block = (b, 8 i-rows, 1 head).
// Lane mapping: lane = (j8, dc): 8 dc-lanes cover one j's 128B d-row.
// scores[i,j] = sum_d q[j,d] k[i,d] rpe[i,j,d] / sqrt(D); mask j<station | j==i.
// ---------------------------------------------------------------------------
__global__ __launch_bounds__(256, 4) void attn_kernel(
    const float* __restrict__ rpe, const float* __restrict__ q_ws,
    const float* __restrict__ k_ws, const float* __restrict__ v_ws,
    const int* __restrict__ station_p, float* __restrict__ o_ws)
{
  __shared__ float p_smem[TI * S_];     // 16 KB: p rows; reused as redv later
  __shared__ float sums[TI];

  const int tid  = threadIdx.x;
  const int w    = tid >> 6, lane = tid & 63;
  const int j8   = lane >> 3, dc = lane & 7;
  const int n    = blockIdx.x;
  const int h    = (n >> 3) & 7;
  const int t    = (n & 7) | ((n >> 6) << 3);      // 0..127 tile id
  const int b    = t >> 6;
  const int i0   = (t & 63) * TI;

  int station = station_p[0];
  station = station > S_ ? S_ : (station < 0 ? 0 : station);

  const float* qb = q_ws + (size_t)((b * H_ + h) * S_) * D_;
  const float* kb = k_ws + (size_t)((b * H_ + h) * S_ + i0) * D_;
  const float* vb = v_ws + (size_t)((b * H_ + h) * S_) * D_;
  const float* rb = rpe + ((size_t)b * S_ + i0) * S_ * D_;
  const float sc = 0.17677669529663687f;   // 1/sqrt(32)

  // K fragments: kf[ii] = k[i0+ii][dc*4 .. dc*4+4)
  float4 kf[TI];
  #pragma unroll
  for (int ii = 0; ii < TI; ++ii)
    kf[ii] = *reinterpret_cast<const float4*>(kb + ii * D_ + dc * 4);

  // ---- scores: wave w covers j in {w*8+pass*32 + j8} ----
  for (int jb = w * 8; jb < station; jb += 32) {
    const int j  = jb + j8;
    const int jc = j < S_ ? j : S_ - 1;            // clamp (partial-pass safety)
    const float4 q4 = *reinterpret_cast<const float4*>(qb + jc * D_ + dc * 4);
    #pragma unroll
    for (int ii = 0; ii < TI; ++ii) {
      const float4 rv = *reinterpret_cast<const float4*>(
          rb + ii * (S_ * D_) + jc * D_ + dc * 4);
      float s = q4.x * kf[ii].x * rv.x;
      s = fmaf(q4.y * kf[ii].y, rv.y, s);
      s = fmaf(q4.z * kf[ii].z, rv.z, s);
      s = fmaf(q4.w * kf[ii].w, rv.w, s);
      s = red8(s);
      if (dc == 0 && j < station) p_smem[ii * S_ + j] = s * sc;
    }
  }
  // diag cells beyond the station range (wave 0; thread (j8,dc) -> cell ii=j8)
  if (w == 0) {
    const int j = i0 + j8;
    if (j >= station) {
      const float4 q4 = *reinterpret_cast<const float4*>(qb + j * D_ + dc * 4);
      const float4 k4 = *reinterpret_cast<const float4*>(kb + j8 * D_ + dc * 4);
      const float4 rv = *reinterpret_cast<const float4*>(
          rb + j8 * (S_ * D_) + j * D_ + dc * 4);
      float s = q4.x * k4.x * rv.x;
      s = fmaf(q4.y * k4.y, rv.y, s);
      s = fmaf(q4.z * k4.z, rv.z, s);
      s = fmaf(q4.w * k4.w, rv.w, s);
      s = red8(s);
      if (dc == 0) p_smem[j8 * S_ + j] = s * sc;
    }
  }
  __syncthreads();

  // ---- softmax: wave w handles rows w and w+4 ----
  #pragma unroll
  for (int k = 0; k < 2; ++k) {
    const int r  = w + k * 4;
    const int ig = i0 + r;
    const bool dx = (ig >= station);
    float m = -1e30f;
    for (int jj = lane; jj < station; jj += 64) m = fmaxf(m, p_smem[r * S_ + jj]);
    const float dv = dx ? p_smem[r * S_ + ig] : -1e30f;
    m = fmaxf(m, dv);
    #pragma unroll
    for (int o = 32; o; o >>= 1) m = fmaxf(m, __shfl_xor(m, o, 64));
    float sum = 0.f;
    for (int jj = lane; jj < station; jj += 64) {
      const float e = __expf(p_smem[r * S_ + jj] - m);
      p_smem[r * S_ + jj] = e;
      sum += e;
    }
    #pragma unroll
    for (int o = 32; o; o >>= 1) sum += __shfl_xor(sum, o, 64);
    if (dx) {
      const float e = __expf(dv - m);
      sum += e;
      if (lane == 0) p_smem[r * S_ + ig] = e;
    }
    if (lane == 0) sums[r] = sum;
  }
  __syncthreads();

  // ---- attn @ V: thread (j8,dc) accumulates its j-slice for all 8 rows ----
  float4 acc[TI];
  #pragma unroll
  for (int ii = 0; ii < TI; ++ii) acc[ii] = make_float4(0.f, 0.f, 0.f, 0.f);

  for (int jb = w * 8; jb < station; jb += 32) {
    const int j  = jb + j8;
    const int jc = j < S_ ? j : S_ - 1;
    const float4 v4 = *reinterpret_cast<const float4*>(vb + jc * D_ + dc * 4);
    #pragma unroll
    for (int ii = 0; ii < TI; ++ii) {
      float pv = 0.f;
      if (j < station) pv = p_smem[ii * S_ + j];   // broadcast (8 dup lanes)
      acc[ii].x = fmaf(pv, v4.x, acc[ii].x);
      acc[ii].y = fmaf(pv, v4.y, acc[ii].y);
      acc[ii].z = fmaf(pv, v4.z, acc[ii].z);
      acc[ii].w = fmaf(pv, v4.w, acc[ii].w);
    }
  }
  // diag contributions (added exactly once: wave 0, j8==0 lanes)
  if (w == 0 && j8 == 0) {
    #pragma unroll
    for (int ii = 0; ii < TI; ++ii) {
      const int ig = i0 + ii;
      if (ig >= station) {
        const float pv = p_smem[ii * S_ + ig];
        const float4 v4 = *reinterpret_cast<const float4*>(vb + ig * D_ + dc * 4);
        acc[ii].x = fmaf(pv, v4.x, acc[ii].x);
        acc[ii].y = fmaf(pv, v4.y, acc[ii].y);
        acc[ii].z = fmaf(pv, v4.z, acc[ii].z);
        acc[ii].w = fmaf(pv, v4.w, acc[ii].w);
      }
    }
  }
  __syncthreads();   // all p_smem reads complete before reuse as redv

  // ---- reduce over (w, j8): shfl-pair then LDS tree (reusing p_smem) ----
  float4* redv = reinterpret_cast<float4*>(p_smem);   // [(w*4+j8h)*8+ii][dc]
  #pragma unroll
  for (int ii = 0; ii < TI; ++ii) {
    float4 a = acc[ii];
    a.x += __shfl_xor(a.x, 8);
    a.y += __shfl_xor(a.y, 8);
    a.z += __shfl_xor(a.z, 8);
    a.w += __shfl_xor(a.w, 8);
    if ((j8 & 1) == 0)
      redv[((w * 4 + (j8 >> 1)) * 8 + ii) * 8 + dc] = a;
  }
  __syncthreads();
  if (tid < 64) {
    const int ii = tid >> 3, d4 = tid & 7;
    float4 a = make_float4(0.f, 0.f, 0.f, 0.f);
    #pragma unroll
    for (int g = 0; g < 16; ++g) {
      const float4 x = redv[(g * 8 + ii) * 8 + d4];
      a.x += x.x; a.y += x.y; a.z += x.z; a.w += x.w;
    }
    const float inv = 1.f / sums[ii];
    a.x *= inv; a.y *= inv; a.z *= inv; a.w *= inv;
    reinterpret_cast<float4*>(
        o_ws + (size_t)((b * H_ + h) * S_ + i0 + ii) * D_)[d4] = a;
  }
}

// ---------------------------------------------------------------------------
// Kernel C: ctx = O @ fc_w + fc_b + hidden, then LayerNorm.
// grid = B*S/NROW, block = 256 (thread per output column m).
// ---------------------------------------------------------------------------
__global__ __launch_bounds__(256) void fc_ln_kernel(
    const float* __restrict__ o_ws, const float* __restrict__ fc_w,
    const float* __restrict__ fc_b, const float* __restrict__ hid,
    const float* __restrict__ ln_w, const float* __restrict__ ln_b,
    float* __restrict__ out)
{
  __shared__ float orow[NROW][HD_];
  __shared__ float red[NROW][4];
  const int tid = threadIdx.x;
  const int r0 = blockIdx.x * NROW;

  for (int idx = tid; idx < NROW * HD_; idx += 256) {
    const int r = idx >> 8, m = idx & 255;
    const int g = r0 + r;
    const int b = g >> 9, i = g & (S_ - 1);
    orow[r][m] = o_ws[((b * H_ + (m >> 5)) * S_ + i) * D_ + (m & 31)];
  }
  __syncthreads();

  float acc[NROW] = {0.f, 0.f, 0.f, 0.f};
  const float* wp = fc_w + tid;
  #pragma unroll 8
  for (int n4 = 0; n4 < HD_ / 4; ++n4) {
    const float w0 = wp[(4 * n4 + 0) * DM_];
    const float w1 = wp[(4 * n4 + 1) * DM_];
    const float w2 = wp[(4 * n4 + 2) * DM_];
    const float w3 = wp[(4 * n4 + 3) * DM_];
    #pragma unroll
    for (int r = 0; r < NROW; ++r) {
      const float4 ov = reinterpret_cast<const float4*>(&orow[r][0])[n4];
      acc[r] = fmaf(ov.x, w0, acc[r]);
      acc[r] = fmaf(ov.y, w1, acc[r]);
      acc[r] = fmaf(ov.z, w2, acc[r]);
      acc[r] = fmaf(ov.w, w3, acc[r]);
    }
  }
  const float bias = fc_b[tid];
  #pragma unroll
  for (int r = 0; r < NROW; ++r) acc[r] += bias + hid[(r0 + r) * DM_ + tid];

  // ---- LayerNorm over DM per row ----
  const int w = tid >> 6, lane = tid & 63;
  float mu[NROW];
  #pragma unroll
  for (int r = 0; r < NROW; ++r) {
    float s = acc[r];
    #pragma unroll
    for (int o = 32; o; o >>= 1) s += __shfl_xor(s, o, 64);
    if (lane == 0) red[r][w] = s;
  }
  __syncthreads();
  #pragma unroll
  for (int r = 0; r < NROW; ++r)
    mu[r] = (red[r][0] + red[r][1] + red[r][2] + red[r][3]) * (1.f / DM_);
  __syncthreads();
  #pragma unroll
  for (int r = 0; r < NROW; ++r) {
    const float dd = acc[r] - mu[r];
    float s = dd * dd;
    #pragma unroll
    for (int o = 32; o; o >>= 1) s += __shfl_xor(s, o, 64);
    if (lane == 0) red[r][w] = s;
  }
  __syncthreads();
  const float lw = ln_w[tid], lb = ln_b[tid];
  #pragma unroll
  for (int r = 0; r < NROW; ++r) {
    const float var = (red[r][0] + red[r][1] + red[r][2] + red[r][3]) * (1.f / DM_);
    out[(r0 + r) * DM_ + tid] =
        (acc[r] - mu[r]) * rsqrtf(var + 1e-6f) * lw + lb;
  }
}

// ---------------------------------------------------------------------------
extern "C" void kernel_launch(void* const* d_in, const int* in_sizes, int n_in,
                              void* d_out, int out_size, void* d_ws, size_t ws_size,
                              hipStream_t stream) {
  const float* hid = (const float*)d_in[0];
  const float* rpe = (const float*)d_in[1];
  const float* wq  = (const float*)d_in[2];
  const float* wk  = (const float*)d_in[3];
  const float* wv  = (const float*)d_in[4];
  const float* fcw = (const float*)d_in[5];
  const float* fcb = (const float*)d_in[6];
  const float* lnw = (const float*)d_in[7];
  const float* lnb = (const float*)d_in[8];
  const int* station = (const int*)d_in[9];
  float* out = (float*)d_out;

  const size_t per = (size_t)B_ * H_ * S_ * D_;   // 262144 floats
  float* q_ws = (float*)d_ws;
  float* k_ws = q_ws + per;
  float* v_ws = k_ws + per;
  float* o_ws = v_ws + per;

  dim3 gA(B_ * S_ / NROW, 3);
  qkv_kernel<<<gA, 256, 0, stream>>>(hid, wq, wk, wv, q_ws, k_ws, v_ws);
  attn_kernel<<<B_ * (S_ / TI) * H_, 256, 0, stream>>>(
      rpe, q_ws, k_ws, v_ws, station, o_ws);
  fc_ln_kernel<<<B_ * S_ / NROW, 256, 0, stream>>>(o_ws, fcw, fcb, hid, lnw, lnb, out);
}

// Round 7
// 176.938 us; speedup vs baseline: 1.0809x; 1.0061x over previous
//
#include <hip/hip_runtime.h>
#include <hip/hip_bf16.h>

#define B_  2
#define S_  512
#define H_  8
#define D_  32
#define DM_ 256
#define HD_ 256
#define NROW 4
#define TI  4          // i-rows per attention block

// ---------------------------------------------------------------------------
// Kernel A: QKV projection.  grid = (B*S/NROW, 3), block = 256.
// out layout: (b, h, s, d)
// ---------------------------------------------------------------------------
__global__ __launch_bounds__(256) void qkv_kernel(
    const float* __restrict__ hid, const float* __restrict__ wq,
    const float* __restrict__ wk, const float* __restrict__ wv,
    float* __restrict__ qo, float* __restrict__ ko, float* __restrict__ vo)
{
  __shared__ float hs[NROW][DM_];
  const int r0 = blockIdx.x * NROW;                 // global row in [0, B*S)
  const float* w   = (blockIdx.y == 0) ? wq : (blockIdx.y == 1) ? wk : wv;
  float*       out = (blockIdx.y == 0) ? qo : (blockIdx.y == 1) ? ko : vo;
  const int tid = threadIdx.x;

  for (int idx = tid; idx < NROW * DM_; idx += 256)
    hs[idx >> 8][idx & 255] = hid[r0 * DM_ + idx];
  __syncthreads();

  float acc[NROW] = {0.f, 0.f, 0.f, 0.f};
  const float* wp = w + tid;                        // column m = tid
  #pragma unroll 8
  for (int c4 = 0; c4 < DM_ / 4; ++c4) {
    const float w0 = wp[(4 * c4 + 0) * HD_];
    const float w1 = wp[(4 * c4 + 1) * HD_];
    const float w2 = wp[(4 * c4 + 2) * HD_];
    const float w3 = wp[(4 * c4 + 3) * HD_];
    #pragma unroll
    for (int r = 0; r < NROW; ++r) {
      const float4 hv = reinterpret_cast<const float4*>(&hs[r][0])[c4];
      acc[r] = fmaf(hv.x, w0, acc[r]);
      acc[r] = fmaf(hv.y, w1, acc[r]);
      acc[r] = fmaf(hv.z, w2, acc[r]);
      acc[r] = fmaf(hv.w, w3, acc[r]);
    }
  }
  const int h = tid >> 5, d = tid & 31;
  #pragma unroll
  for (int r = 0; r < NROW; ++r) {
    const int g = r0 + r;
    const int b = g >> 9, s = g & (S_ - 1);
    out[((b * H_ + h) * S_ + s) * D_ + d] = acc[r];
  }
}

// 8-lane (dc-group) sum reduction on the VALU pipe via DPP.
// Valid result at lanes with (lane&7)==0.
__device__ __forceinline__ float red8(float x) {
  int i;
  i = __builtin_amdgcn_mov_dpp(__float_as_int(x), 0xB1, 0xf, 0xf, true); // quad_perm xor1
  x += __int_as_float(i);
  i = __builtin_amdgcn_mov_dpp(__float_as_int(x), 0x4E, 0xf, 0xf, true); // quad_perm xor2
  x += __int_as_float(i);
  i = __builtin_amdgcn_mov_dpp(__float_as_int(x), 0x124, 0xf, 0xf, true); // row_ror:4
  x += __int_as_float(i);
  return x;
}

// ---------------------------------------------------------------------------
// Kernel B: scores + mask + softmax + attn@V.  All hot global loads COALESCED.
// 2048 blocks (XCD swizzle: 8 head-blocks of one rpe tile -> same XCD),
// 256 threads (4 waves), 8 blocks/CU.  Block = (b, 4 i-rows, 1 head).
// Lane mapping: lane = (j8, dc): 8 dc-lanes cover one j's 128B d-row.
// scores[i,j] = sum_d q[j,d] k[i,d] rpe[i,j,d] / sqrt(D); mask j<station | j==i.
// ---------------------------------------------------------------------------
__global__ __launch_bounds__(256, 8) void attn_kernel(
    const float* __restrict__ rpe, const float* __restrict__ q_ws,
    const float* __restrict__ k_ws, const float* __restrict__ v_ws,
    const int* __restrict__ station_p, float* __restrict__ o_ws)
{
  __shared__ float p_smem[TI * S_];     // 8 KB: p rows; reused as redv later
  __shared__ float sums[TI];

  const int tid  = threadIdx.x;
  const int w    = tid >> 6, lane = tid & 63;
  const int j8   = lane >> 3, dc = lane & 7;
  const int n    = blockIdx.x;                     // 0..2047
  const int h    = (n >> 3) & 7;
  const int t    = (n & 7) | ((n >> 6) << 3);      // 0..255 tile id
  const int b    = t >> 7;
  const int i0   = (t & 127) * TI;

  int station = station_p[0];
  station = station > S_ ? S_ : (station < 0 ? 0 : station);

  const float* qb = q_ws + (size_t)((b * H_ + h) * S_) * D_;
  const float* kb = k_ws + (size_t)((b * H_ + h) * S_ + i0) * D_;
  const float* vb = v_ws + (size_t)((b * H_ + h) * S_) * D_;
  const float* rb = rpe + ((size_t)b * S_ + i0) * S_ * D_;
  const float sc = 0.17677669529663687f;   // 1/sqrt(32)

  // K fragments: kf[ii] = k[i0+ii][dc*4 .. dc*4+4)
  float4 kf[TI];
  #pragma unroll
  for (int ii = 0; ii < TI; ++ii)
    kf[ii] = *reinterpret_cast<const float4*>(kb + ii * D_ + dc * 4);

  // ---- scores: wave w covers j in {w*8+pass*32 + j8} ----
  for (int jb = w * 8; jb < station; jb += 32) {
    const int j  = jb + j8;
    const int jc = j < S_ ? j : S_ - 1;            // clamp (partial-pass safety)
    // batch-issue all loads for this pass (independent, pipelined)
    const float4 q4 = *reinterpret_cast<const float4*>(qb + jc * D_ + dc * 4);
    float4 rv[TI];
    #pragma unroll
    for (int ii = 0; ii < TI; ++ii)
      rv[ii] = *reinterpret_cast<const float4*>(
          rb + ii * (S_ * D_) + jc * D_ + dc * 4);
    #pragma unroll
    for (int ii = 0; ii < TI; ++ii) {
      float s = q4.x * kf[ii].x * rv[ii].x;
      s = fmaf(q4.y * kf[ii].y, rv[ii].y, s);
      s = fmaf(q4.z * kf[ii].z, rv[ii].z, s);
      s = fmaf(q4.w * kf[ii].w, rv[ii].w, s);
      s = red8(s);
      if (dc == 0 && j < station) p_smem[ii * S_ + j] = s * sc;
    }
  }
  // diag cells beyond the station range (wave 0, lanes j8 < TI; cell ii=j8)
  if (w == 0 && j8 < TI) {
    const int j = i0 + j8;
    if (j >= station) {
      const float4 q4 = *reinterpret_cast<const float4*>(qb + j * D_ + dc * 4);
      const float4 rv = *reinterpret_cast<const float4*>(
          rb + j8 * (S_ * D_) + j * D_ + dc * 4);
      float s = q4.x * kf[j8].x * rv.x;
      s = fmaf(q4.y * kf[j8].y, rv.y, s);
      s = fmaf(q4.z * kf[j8].z, rv.z, s);
      s = fmaf(q4.w * kf[j8].w, rv.w, s);
      s = red8(s);
      if (dc == 0) p_smem[j8 * S_ + j] = s * sc;
    }
  }
  __syncthreads();

  // ---- softmax: wave w handles row w ----
  {
    const int r  = w;
    const int ig = i0 + r;
    const bool dx = (ig >= station);
    float m = -1e30f;
    for (int jj = lane; jj < station; jj += 64) m = fmaxf(m, p_smem[r * S_ + jj]);
    const float dv = dx ? p_smem[r * S_ + ig] : -1e30f;
    m = fmaxf(m, dv);
    #pragma unroll
    for (int o = 32; o; o >>= 1) m = fmaxf(m, __shfl_xor(m, o, 64));
    float sum = 0.f;
    for (int jj = lane; jj < station; jj += 64) {
      const float e = __expf(p_smem[r * S_ + jj] - m);
      p_smem[r * S_ + jj] = e;
      sum += e;
    }
    #pragma unroll
    for (int o = 32; o; o >>= 1) sum += __shfl_xor(sum, o, 64);
    if (dx) {
      const float e = __expf(dv - m);
      sum += e;
      if (lane == 0) p_smem[r * S_ + ig] = e;
    }
    if (lane == 0) sums[r] = sum;
  }
  __syncthreads();

  // ---- attn @ V: thread (j8,dc) accumulates its j-slice for all 4 rows ----
  float4 acc[TI];
  #pragma unroll
  for (int ii = 0; ii < TI; ++ii) acc[ii] = make_float4(0.f, 0.f, 0.f, 0.f);

  for (int jb = w * 8; jb < station; jb += 32) {
    const int j  = jb + j8;
    const int jc = j < S_ ? j : S_ - 1;
    const float4 v4 = *reinterpret_cast<const float4*>(vb + jc * D_ + dc * 4);
    #pragma unroll
    for (int ii = 0; ii < TI; ++ii) {
      float pv = 0.f;
      if (j < station) pv = p_smem[ii * S_ + j];   // broadcast (8 dup lanes)
      acc[ii].x = fmaf(pv, v4.x, acc[ii].x);
      acc[ii].y = fmaf(pv, v4.y, acc[ii].y);
      acc[ii].z = fmaf(pv, v4.z, acc[ii].z);
      acc[ii].w = fmaf(pv, v4.w, acc[ii].w);
    }
  }
  // diag contributions (added exactly once: wave 0, j8==0 lanes)
  if (w == 0 && j8 == 0) {
    #pragma unroll
    for (int ii = 0; ii < TI; ++ii) {
      const int ig = i0 + ii;
      if (ig >= station) {
        const float pv = p_smem[ii * S_ + ig];
        const float4 v4 = *reinterpret_cast<const float4*>(vb + ig * D_ + dc * 4);
        acc[ii].x = fmaf(pv, v4.x, acc[ii].x);
        acc[ii].y = fmaf(pv, v4.y, acc[ii].y);
        acc[ii].z = fmaf(pv, v4.z, acc[ii].z);
        acc[ii].w = fmaf(pv, v4.w, acc[ii].w);
      }
    }
  }
  __syncthreads();   // all p_smem reads complete before reuse as redv

  // ---- reduce over (w, j8): shfl-pair then LDS tree (reusing p_smem) ----
  // 16 groups (w, j8/2) x TI rows x 8 dc, float4 each = 8 KB
  float4* redv = reinterpret_cast<float4*>(p_smem);
  #pragma unroll
  for (int ii = 0; ii < TI; ++ii) {
    float4 a = acc[ii];
    a.x += __shfl_xor(a.x, 8);
    a.y += __shfl_xor(a.y, 8);
    a.z += __shfl_xor(a.z, 8);
    a.w += __shfl_xor(a.w, 8);
    if ((j8 & 1) == 0)
      redv[((w * 4 + (j8 >> 1)) * TI + ii) * 8 + dc] = a;
  }
  __syncthreads();
  if (tid < TI * 8) {
    const int ii = tid >> 3, d4 = tid & 7;
    float4 a = make_float4(0.f, 0.f, 0.f, 0.f);
    #pragma unroll
    for (int g = 0; g < 16; ++g) {
      const float4 x = redv[(g * TI + ii) * 8 + d4];
      a.x += x.x; a.y += x.y; a.z += x.z; a.w += x.w;
    }
    const float inv = 1.f / sums[ii];
    a.x *= inv; a.y *= inv; a.z *= inv; a.w *= inv;
    reinterpret_cast<float4*>(
        o_ws + (size_t)((b * H_ + h) * S_ + i0 + ii) * D_)[d4] = a;
  }
}

// ---------------------------------------------------------------------------
// Kernel C: ctx = O @ fc_w + fc_b + hidden, then LayerNorm.
// grid = B*S/NROW, block = 256 (thread per output column m).
// ---------------------------------------------------------------------------
__global__ __launch_bounds__(256) void fc_ln_kernel(
    const float* __restrict__ o_ws, const float* __restrict__ fc_w,
    const float* __restrict__ fc_b, const float* __restrict__ hid,
    const float* __restrict__ ln_w, const float* __restrict__ ln_b,
    float* __restrict__ out)
{
  __shared__ float orow[NROW][HD_];
  __shared__ float red[NROW][4];
  const int tid = threadIdx.x;
  const int r0 = blockIdx.x * NROW;

  for (int idx = tid; idx < NROW * HD_; idx += 256) {
    const int r = idx >> 8, m = idx & 255;
    const int g = r0 + r;
    const int b = g >> 9, i = g & (S_ - 1);
    orow[r][m] = o_ws[((b * H_ + (m >> 5)) * S_ + i) * D_ + (m & 31)];
  }
  __syncthreads();

  float acc[NROW] = {0.f, 0.f, 0.f, 0.f};
  const float* wp = fc_w + tid;
  #pragma unroll 8
  for (int n4 = 0; n4 < HD_ / 4; ++n4) {
    const float w0 = wp[(4 * n4 + 0) * DM_];
    const float w1 = wp[(4 * n4 + 1) * DM_];
    const float w2 = wp[(4 * n4 + 2) * DM_];
    const float w3 = wp[(4 * n4 + 3) * DM_];
    #pragma unroll
    for (int r = 0; r < NROW; ++r) {
      const float4 ov = reinterpret_cast<const float4*>(&orow[r][0])[n4];
      acc[r] = fmaf(ov.x, w0, acc[r]);
      acc[r] = fmaf(ov.y, w1, acc[r]);
      acc[r] = fmaf(ov.z, w2, acc[r]);
      acc[r] = fmaf(ov.w, w3, acc[r]);
    }
  }
  const float bias = fc_b[tid];
  #pragma unroll
  for (int r = 0; r < NROW; ++r) acc[r] += bias + hid[(r0 + r) * DM_ + tid];

  // ---- LayerNorm over DM per row ----
  const int w = tid >> 6, lane = tid & 63;
  float mu[NROW];
  #pragma unroll
  for (int r = 0; r < NROW; ++r) {
    float s = acc[r];
    #pragma unroll
    for (int o = 32; o; o >>= 1) s += __shfl_xor(s, o, 64);
    if (lane == 0) red[r][w] = s;
  }
  __syncthreads();
  #pragma unroll
  for (int r = 0; r < NROW; ++r)
    mu[r] = (red[r][0] + red[r][1] + red[r][2] + red[r][3]) * (1.f / DM_);
  __syncthreads();
  #pragma unroll
  for (int r = 0; r < NROW; ++r) {
    const float dd = acc[r] - mu[r];
    float s = dd * dd;
    #pragma unroll
    for (int o = 32; o; o >>= 1) s += __shfl_xor(s, o, 64);
    if (lane == 0) red[r][w] = s;
  }
  __syncthreads();
  const float lw = ln_w[tid], lb = ln_b[tid];
  #pragma unroll
  for (int r = 0; r < NROW; ++r) {
    const float var = (red[r][0] + red[r][1] + red[r][2] + red[r][3]) * (1.f / DM_);
    out[(r0 + r) * DM_ + tid] =
        (acc[r] - mu[r]) * rsqrtf(var + 1e-6f) * lw + lb;
  }
}

// ---------------------------------------------------------------------------
extern "C" void kernel_launch(void* const* d_in, const int* in_sizes, int n_in,
                              void* d_out, int out_size, void* d_ws, size_t ws_size,
                              hipStream_t stream) {
  const float* hid = (const float*)d_in[0];
  const float* rpe = (const float*)d_in[1];
  const float* wq  = (const float*)d_in[2];
  const float* wk  = (const float*)d_in[3];
  const float* wv  = (const float*)d_in[4];
  const float* fcw = (const float*)d_in[5];
  const float* fcb = (const float*)d_in[6];
  const float* lnw = (const float*)d_in[7];
  const float* lnb = (const float*)d_in[8];
  const int* station = (const int*)d_in[9];
  float* out = (float*)d_out;

  const size_t per = (size_t)B_ * H_ * S_ * D_;   // 262144 floats
  float* q_ws = (float*)d_ws;
  float* k_ws = q_ws + per;
  float* v_ws = k_ws + per;
  float* o_ws = v_ws + per;

  dim3 gA(B_ * S_ / NROW, 3);
  qkv_kernel<<<gA, 256, 0, stream>>>(hid, wq, wk, wv, q_ws, k_ws, v_ws);
  attn_kernel<<<B_ * (S_ / TI) * H_, 256, 0, stream>>>(
      rpe, q_ws, k_ws, v_ws, station, o_ws);
  fc_ln_kernel<<<B_ * S_ / NROW, 256, 0, stream>>>(o_ws, fcw, fcb, hid, lnw, lnb, out);
}

// Round 8
// 157.738 us; speedup vs baseline: 1.2124x; 1.1217x over previous
//
#include <hip/hip_runtime.h>
#include <hip/hip_bf16.h>

#define B_  2
#define S_  512
#define H_  8
#define D_  32
#define DM_ 256
#define HD_ 256
#define NROW 4
#define TI  4          // i-rows per attention block

// ---------------------------------------------------------------------------
// Kernel A: QKV projection.  grid = (B*S/NROW, 3), block = 256.
// out layout: (b, h, s, d)
// ---------------------------------------------------------------------------
__global__ __launch_bounds__(256) void qkv_kernel(
    const float* __restrict__ hid, const float* __restrict__ wq,
    const float* __restrict__ wk, const float* __restrict__ wv,
    float* __restrict__ qo, float* __restrict__ ko, float* __restrict__ vo)
{
  __shared__ float hs[NROW][DM_];
  const int r0 = blockIdx.x * NROW;                 // global row in [0, B*S)
  const float* w   = (blockIdx.y == 0) ? wq : (blockIdx.y == 1) ? wk : wv;
  float*       out = (blockIdx.y == 0) ? qo : (blockIdx.y == 1) ? ko : vo;
  const int tid = threadIdx.x;

  for (int idx = tid; idx < NROW * DM_; idx += 256)
    hs[idx >> 8][idx & 255] = hid[r0 * DM_ + idx];
  __syncthreads();

  float acc[NROW] = {0.f, 0.f, 0.f, 0.f};
  const float* wp = w + tid;                        // column m = tid
  #pragma unroll 8
  for (int c4 = 0; c4 < DM_ / 4; ++c4) {
    const float w0 = wp[(4 * c4 + 0) * HD_];
    const float w1 = wp[(4 * c4 + 1) * HD_];
    const float w2 = wp[(4 * c4 + 2) * HD_];
    const float w3 = wp[(4 * c4 + 3) * HD_];
    #pragma unroll
    for (int r = 0; r < NROW; ++r) {
      const float4 hv = reinterpret_cast<const float4*>(&hs[r][0])[c4];
      acc[r] = fmaf(hv.x, w0, acc[r]);
      acc[r] = fmaf(hv.y, w1, acc[r]);
      acc[r] = fmaf(hv.z, w2, acc[r]);
      acc[r] = fmaf(hv.w, w3, acc[r]);
    }
  }
  const int h = tid >> 5, d = tid & 31;
  #pragma unroll
  for (int r = 0; r < NROW; ++r) {
    const int g = r0 + r;
    const int b = g >> 9, s = g & (S_ - 1);
    out[((b * H_ + h) * S_ + s) * D_ + d] = acc[r];
  }
}

// 8-lane (dc-group) sum reduction on the VALU pipe via DPP.
// Valid result at lanes with (lane&7)==0.
__device__ __forceinline__ float red8(float x) {
  int i;
  i = __builtin_amdgcn_mov_dpp(__float_as_int(x), 0xB1, 0xf, 0xf, true); // quad_perm xor1
  x += __int_as_float(i);
  i = __builtin_amdgcn_mov_dpp(__float_as_int(x), 0x4E, 0xf, 0xf, true); // quad_perm xor2
  x += __int_as_float(i);
  i = __builtin_amdgcn_mov_dpp(__float_as_int(x), 0x124, 0xf, 0xf, true); // row_ror:4
  x += __int_as_float(i);
  return x;
}

// ---------------------------------------------------------------------------
// Kernel B: scores + mask + softmax + attn@V.  All hot global loads COALESCED.
// 2048 blocks (XCD swizzle: 8 head-blocks of one rpe tile -> same XCD),
// 256 threads (4 waves), 8 blocks/CU.  Block = (b, 4 i-rows, 1 head).
// Lane mapping: lane = (j8, dc): 8 dc-lanes cover one j's 128B d-row.
// scores[i,j] = sum_d q[j,d] k[i,d] rpe[i,j,d] / sqrt(D); mask j<station | j==i.
// NOTE: no dynamically-indexed register arrays (kf[j8] in R7 demoted the
// whole array to scratch -> 33 MB of spill traffic).
// ---------------------------------------------------------------------------
__global__ __launch_bounds__(256, 8) void attn_kernel(
    const float* __restrict__ rpe, const float* __restrict__ q_ws,
    const float* __restrict__ k_ws, const float* __restrict__ v_ws,
    const int* __restrict__ station_p, float* __restrict__ o_ws)
{
  __shared__ float p_smem[TI * S_];     // 8 KB: p rows; reused as redv later
  __shared__ float sums[TI];

  const int tid  = threadIdx.x;
  const int w    = tid >> 6, lane = tid & 63;
  const int j8   = lane >> 3, dc = lane & 7;
  const int n    = blockIdx.x;                     // 0..2047
  const int h    = (n >> 3) & 7;
  const int t    = (n & 7) | ((n >> 6) << 3);      // 0..255 tile id
  const int b    = t >> 7;
  const int i0   = (t & 127) * TI;

  int station = station_p[0];
  station = station > S_ ? S_ : (station < 0 ? 0 : station);

  const float* qb = q_ws + (size_t)((b * H_ + h) * S_) * D_;
  const float* kb = k_ws + (size_t)((b * H_ + h) * S_ + i0) * D_;
  const float* vb = v_ws + (size_t)((b * H_ + h) * S_) * D_;
  const float* rb = rpe + ((size_t)b * S_ + i0) * S_ * D_;
  const float sc = 0.17677669529663687f;   // 1/sqrt(32)

  // K fragments: kf[ii] = k[i0+ii][dc*4 .. dc*4+4)  (constant indices ONLY)
  float4 kf[TI];
  #pragma unroll
  for (int ii = 0; ii < TI; ++ii)
    kf[ii] = *reinterpret_cast<const float4*>(kb + ii * D_ + dc * 4);

  // ---- scores: wave w covers j in {w*8+pass*32 + j8} ----
  for (int jb = w * 8; jb < station; jb += 32) {
    const int j  = jb + j8;
    const int jc = j < S_ ? j : S_ - 1;            // clamp (partial-pass safety)
    // batch-issue all loads for this pass (independent, pipelined)
    const float4 q4 = *reinterpret_cast<const float4*>(qb + jc * D_ + dc * 4);
    float4 rv[TI];
    #pragma unroll
    for (int ii = 0; ii < TI; ++ii)
      rv[ii] = *reinterpret_cast<const float4*>(
          rb + ii * (S_ * D_) + jc * D_ + dc * 4);
    #pragma unroll
    for (int ii = 0; ii < TI; ++ii) {
      float s = q4.x * kf[ii].x * rv[ii].x;
      s = fmaf(q4.y * kf[ii].y, rv[ii].y, s);
      s = fmaf(q4.z * kf[ii].z, rv[ii].z, s);
      s = fmaf(q4.w * kf[ii].w, rv[ii].w, s);
      s = red8(s);
      if (dc == 0 && j < station) p_smem[ii * S_ + j] = s * sc;
    }
  }
  // diag cells beyond the station range (wave 0, lanes j8 < TI; cell ii=j8).
  // K fragment re-loaded from global here (runtime row index j8) to avoid
  // dynamic indexing into the kf register array.
  if (w == 0 && j8 < TI) {
    const int j = i0 + j8;
    if (j >= station) {
      const float4 q4 = *reinterpret_cast<const float4*>(qb + j * D_ + dc * 4);
      const float4 k4 = *reinterpret_cast<const float4*>(kb + j8 * D_ + dc * 4);
      const float4 rv = *reinterpret_cast<const float4*>(
          rb + j8 * (S_ * D_) + j * D_ + dc * 4);
      float s = q4.x * k4.x * rv.x;
      s = fmaf(q4.y * k4.y, rv.y, s);
      s = fmaf(q4.z * k4.z, rv.z, s);
      s = fmaf(q4.w * k4.w, rv.w, s);
      s = red8(s);
      if (dc == 0) p_smem[j8 * S_ + j] = s * sc;
    }
  }
  __syncthreads();

  // ---- softmax: wave w handles row w ----
  {
    const int r  = w;
    const int ig = i0 + r;
    const bool dx = (ig >= station);
    float m = -1e30f;
    for (int jj = lane; jj < station; jj += 64) m = fmaxf(m, p_smem[r * S_ + jj]);
    const float dv = dx ? p_smem[r * S_ + ig] : -1e30f;
    m = fmaxf(m, dv);
    #pragma unroll
    for (int o = 32; o; o >>= 1) m = fmaxf(m, __shfl_xor(m, o, 64));
    float sum = 0.f;
    for (int jj = lane; jj < station; jj += 64) {
      const float e = __expf(p_smem[r * S_ + jj] - m);
      p_smem[r * S_ + jj] = e;
      sum += e;
    }
    #pragma unroll
    for (int o = 32; o; o >>= 1) sum += __shfl_xor(sum, o, 64);
    if (dx) {
      const float e = __expf(dv - m);
      sum += e;
      if (lane == 0) p_smem[r * S_ + ig] = e;
    }
    if (lane == 0) sums[r] = sum;
  }
  __syncthreads();

  // ---- attn @ V: thread (j8,dc) accumulates its j-slice for all 4 rows ----
  float4 acc[TI];
  #pragma unroll
  for (int ii = 0; ii < TI; ++ii) acc[ii] = make_float4(0.f, 0.f, 0.f, 0.f);

  for (int jb = w * 8; jb < station; jb += 32) {
    const int j  = jb + j8;
    const int jc = j < S_ ? j : S_ - 1;
    const float4 v4 = *reinterpret_cast<const float4*>(vb + jc * D_ + dc * 4);
    #pragma unroll
    for (int ii = 0; ii < TI; ++ii) {
      float pv = 0.f;
      if (j < station) pv = p_smem[ii * S_ + j];   // broadcast (8 dup lanes)
      acc[ii].x = fmaf(pv, v4.x, acc[ii].x);
      acc[ii].y = fmaf(pv, v4.y, acc[ii].y);
      acc[ii].z = fmaf(pv, v4.z, acc[ii].z);
      acc[ii].w = fmaf(pv, v4.w, acc[ii].w);
    }
  }
  // diag contributions (added exactly once: wave 0, j8==0 lanes)
  if (w == 0 && j8 == 0) {
    #pragma unroll
    for (int ii = 0; ii < TI; ++ii) {
      const int ig = i0 + ii;
      if (ig >= station) {
        const float pv = p_smem[ii * S_ + ig];
        const float4 v4 = *reinterpret_cast<const float4*>(vb + ig * D_ + dc * 4);
        acc[ii].x = fmaf(pv, v4.x, acc[ii].x);
        acc[ii].y = fmaf(pv, v4.y, acc[ii].y);
        acc[ii].z = fmaf(pv, v4.z, acc[ii].z);
        acc[ii].w = fmaf(pv, v4.w, acc[ii].w);
      }
    }
  }
  __syncthreads();   // all p_smem reads complete before reuse as redv

  // ---- reduce over (w, j8): shfl-pair then LDS tree (reusing p_smem) ----
  // 16 groups (w, j8/2) x TI rows x 8 dc, float4 each = 8 KB
  float4* redv = reinterpret_cast<float4*>(p_smem);
  #pragma unroll
  for (int ii = 0; ii < TI; ++ii) {
    float4 a = acc[ii];
    a.x += __shfl_xor(a.x, 8);
    a.y += __shfl_xor(a.y, 8);
    a.z += __shfl_xor(a.z, 8);
    a.w += __shfl_xor(a.w, 8);
    if ((j8 & 1) == 0)
      redv[((w * 4 + (j8 >> 1)) * TI + ii) * 8 + dc] = a;
  }
  __syncthreads();
  if (tid < TI * 8) {
    const int ii = tid >> 3, d4 = tid & 7;
    float4 a = make_float4(0.f, 0.f, 0.f, 0.f);
    #pragma unroll
    for (int g = 0; g < 16; ++g) {
      const float4 x = redv[(g * TI + ii) * 8 + d4];
      a.x += x.x; a.y += x.y; a.z += x.z; a.w += x.w;
    }
    const float inv = 1.f / sums[ii];
    a.x *= inv; a.y *= inv; a.z *= inv; a.w *= inv;
    reinterpret_cast<float4*>(
        o_ws + (size_t)((b * H_ + h) * S_ + i0 + ii) * D_)[d4] = a;
  }
}

// ---------------------------------------------------------------------------
// Kernel C: ctx = O @ fc_w + fc_b + hidden, then LayerNorm.
// grid = B*S/NROW, block = 256 (thread per output column m).
// ---------------------------------------------------------------------------
__global__ __launch_bounds__(256) void fc_ln_kernel(
    const float* __restrict__ o_ws, const float* __restrict__ fc_w,
    const float* __restrict__ fc_b, const float* __restrict__ hid,
    const float* __restrict__ ln_w, const float* __restrict__ ln_b,
    float* __restrict__ out)
{
  __shared__ float orow[NROW][HD_];
  __shared__ float red[NROW][4];
  const int tid = threadIdx.x;
  const int r0 = blockIdx.x * NROW;

  for (int idx = tid; idx < NROW * HD_; idx += 256) {
    const int r = idx >> 8, m = idx & 255;
    const int g = r0 + r;
    const int b = g >> 9, i = g & (S_ - 1);
    orow[r][m] = o_ws[((b * H_ + (m >> 5)) * S_ + i) * D_ + (m & 31)];
  }
  __syncthreads();

  float acc[NROW] = {0.f, 0.f, 0.f, 0.f};
  const float* wp = fc_w + tid;
  #pragma unroll 8
  for (int n4 = 0; n4 < HD_ / 4; ++n4) {
    const float w0 = wp[(4 * n4 + 0) * DM_];
    const float w1 = wp[(4 * n4 + 1) * DM_];
    const float w2 = wp[(4 * n4 + 2) * DM_];
    const float w3 = wp[(4 * n4 + 3) * DM_];
    #pragma unroll
    for (int r = 0; r < NROW; ++r) {
      const float4 ov = reinterpret_cast<const float4*>(&orow[r][0])[n4];
      acc[r] = fmaf(ov.x, w0, acc[r]);
      acc[r] = fmaf(ov.y, w1, acc[r]);
      acc[r] = fmaf(ov.z, w2, acc[r]);
      acc[r] = fmaf(ov.w, w3, acc[r]);
    }
  }
  const float bias = fc_b[tid];
  #pragma unroll
  for (int r = 0; r < NROW; ++r) acc[r] += bias + hid[(r0 + r) * DM_ + tid];

  // ---- LayerNorm over DM per row ----
  const int w = tid >> 6, lane = tid & 63;
  float mu[NROW];
  #pragma unroll
  for (int r = 0; r < NROW; ++r) {
    float s = acc[r];
    #pragma unroll
    for (int o = 32; o; o >>= 1) s += __shfl_xor(s, o, 64);
    if (lane == 0) red[r][w] = s;
  }
  __syncthreads();
  #pragma unroll
  for (int r = 0; r < NROW; ++r)
    mu[r] = (red[r][0] + red[r][1] + red[r][2] + red[r][3]) * (1.f / DM_);
  __syncthreads();
  #pragma unroll
  for (int r = 0; r < NROW; ++r) {
    const float dd = acc[r] - mu[r];
    float s = dd * dd;
    #pragma unroll
    for (int o = 32; o; o >>= 1) s += __shfl_xor(s, o, 64);
    if (lane == 0) red[r][w] = s;
  }
  __syncthreads();
  const float lw = ln_w[tid], lb = ln_b[tid];
  #pragma unroll
  for (int r = 0; r < NROW; ++r) {
    const float var = (red[r][0] + red[r][1] + red[r][2] + red[r][3]) * (1.f / DM_);
    out[(r0 + r) * DM_ + tid] =
        (acc[r] - mu[r]) * rsqrtf(var + 1e-6f) * lw + lb;
  }
}

// ---------------------------------------------------------------------------
extern "C" void kernel_launch(void* const* d_in, const int* in_sizes, int n_in,
                              void* d_out, int out_size, void* d_ws, size_t ws_size,
                              hipStream_t stream) {
  const float* hid = (const float*)d_in[0];
  const float* rpe = (const float*)d_in[1];
  const float* wq  = (const float*)d_in[2];
  const float* wk  = (const float*)d_in[3];
  const float* wv  = (const float*)d_in[4];
  const float* fcw = (const float*)d_in[5];
  const float* fcb = (const float*)d_in[6];
  const float* lnw = (const float*)d_in[7];
  const float* lnb = (const float*)d_in[8];
  const int* station = (const int*)d_in[9];
  float* out = (float*)d_out;

  const size_t per = (size_t)B_ * H_ * S_ * D_;   // 262144 floats
  float* q_ws = (float*)d_ws;
  float* k_ws = q_ws + per;
  float* v_ws = k_ws + per;
  float* o_ws = v_ws + per;

  dim3 gA(B_ * S_ / NROW, 3);
  qkv_kernel<<<gA, 256, 0, stream>>>(hid, wq, wk, wv, q_ws, k_ws, v_ws);
  attn_kernel<<<B_ * (S_ / TI) * H_, 256, 0, stream>>>(
      rpe, q_ws, k_ws, v_ws, station, o_ws);
  fc_ln_kernel<<<B_ * S_ / NROW, 256, 0, stream>>>(o_ws, fcw, fcb, hid, lnw, lnb, out);
}

// Round 9
// 156.689 us; speedup vs baseline: 1.2205x; 1.0067x over previous
//
#include <hip/hip_runtime.h>
#include <hip/hip_bf16.h>

#define B_  2
#define S_  512
#define H_  8
#define D_  32
#define DM_ 256
#define HD_ 256
#define NROW 4
#define TI  2          // i-rows per attention block
#define HC  2          // heads per attention block
#define NR  (TI * HC)  // p-rows per block

// ---------------------------------------------------------------------------
// Kernel A: QKV projection.  grid = (B*S/NROW, 3), block = 256.
// out layout: (b, h, s, d).  q is pre-scaled by 1/sqrt(D).
// ---------------------------------------------------------------------------
__global__ __launch_bounds__(256) void qkv_kernel(
    const float* __restrict__ hid, const float* __restrict__ wq,
    const float* __restrict__ wk, const float* __restrict__ wv,
    float* __restrict__ qo, float* __restrict__ ko, float* __restrict__ vo)
{
  __shared__ float hs[NROW][DM_];
  const int r0 = blockIdx.x * NROW;                 // global row in [0, B*S)
  const float* w   = (blockIdx.y == 0) ? wq : (blockIdx.y == 1) ? wk : wv;
  float*       out = (blockIdx.y == 0) ? qo : (blockIdx.y == 1) ? ko : vo;
  const float mulf = (blockIdx.y == 0) ? 0.17677669529663687f : 1.0f;
  const int tid = threadIdx.x;

  for (int idx = tid; idx < NROW * DM_; idx += 256)
    hs[idx >> 8][idx & 255] = hid[r0 * DM_ + idx];
  __syncthreads();

  float acc[NROW] = {0.f, 0.f, 0.f, 0.f};
  const float* wp = w + tid;                        // column m = tid
  #pragma unroll 8
  for (int c4 = 0; c4 < DM_ / 4; ++c4) {
    const float w0 = wp[(4 * c4 + 0) * HD_];
    const float w1 = wp[(4 * c4 + 1) * HD_];
    const float w2 = wp[(4 * c4 + 2) * HD_];
    const float w3 = wp[(4 * c4 + 3) * HD_];
    #pragma unroll
    for (int r = 0; r < NROW; ++r) {
      const float4 hv = reinterpret_cast<const float4*>(&hs[r][0])[c4];
      acc[r] = fmaf(hv.x, w0, acc[r]);
      acc[r] = fmaf(hv.y, w1, acc[r]);
      acc[r] = fmaf(hv.z, w2, acc[r]);
      acc[r] = fmaf(hv.w, w3, acc[r]);
    }
  }
  const int h = tid >> 5, d = tid & 31;
  #pragma unroll
  for (int r = 0; r < NROW; ++r) {
    const int g = r0 + r;
    const int b = g >> 9, s = g & (S_ - 1);
    out[((b * H_ + h) * S_ + s) * D_ + d] = acc[r] * mulf;
  }
}

// 4-lane (quad) butterfly sum via DPP: all 4 lanes of the quad get the sum.
__device__ __forceinline__ float red4(float x) {
  int i;
  i = __builtin_amdgcn_mov_dpp(__float_as_int(x), 0xB1, 0xf, 0xf, true); // quad_perm xor1
  x += __int_as_float(i);
  i = __builtin_amdgcn_mov_dpp(__float_as_int(x), 0x4E, 0xf, 0xf, true); // quad_perm xor2
  x += __int_as_float(i);
  return x;
}

// ---------------------------------------------------------------------------
// Kernel B: scores + mask + softmax + attn@V.  Coalesced loads; 2 heads per
// block share each rpe read (halves L2-side rpe traffic vs HC=1).
// 2048 blocks, XCD-swizzled: the 4 head-group blocks of one (b,i-tile) rpe
// tile get ids 8 apart -> same XCD, adjacent in stream -> rpe L2 reuse.
// 256 threads (4 waves), 4 blocks/CU (128-reg headroom: NO spills).
// Score mapping: lane=(j4,dq), 4 dq-lanes cover one j's 128B d-row (32B each).
// attn@V mapping: lane=(j8,dc), dc*16B slice.
// scores[h,i,j] = sum_d q'[h,j,d] k[h,i,d] rpe[i,j,d]  (q' pre-scaled);
// mask: j < station OR j == i.  p-row r = hh*TI + ii.
// NOTE: register arrays use compile-time indices ONLY (R7: dynamic index
// -> scratch demotion -> 33 MB spill traffic).
// ---------------------------------------------------------------------------
__global__ __launch_bounds__(256, 4) void attn_kernel(
    const float* __restrict__ rpe, const float* __restrict__ q_ws,
    const float* __restrict__ k_ws, const float* __restrict__ v_ws,
    const int* __restrict__ station_p, float* __restrict__ o_ws)
{
  __shared__ float p_smem[NR * S_];     // 8 KB; reused as redv afterwards
  __shared__ float sums[NR];

  const int tid  = threadIdx.x;
  const int w    = tid >> 6, lane = tid & 63;
  const int j4   = lane >> 2, dq = lane & 3;       // score mapping
  const int j8   = lane >> 3, dc = lane & 7;       // attn@V mapping
  const int n    = blockIdx.x;                     // 0..2047
  const int hg   = (n >> 3) & 3;
  const int t    = (n & 7) | ((n >> 5) << 3);      // 0..511 tile id
  const int b    = t >> 8;
  const int i0   = (t & 255) * TI;
  const int h0   = hg * HC;
  const int HS   = S_ * D_;                        // head / i-row stride

  int station = station_p[0];
  station = station > S_ ? S_ : (station < 0 ? 0 : station);

  const float* qb = q_ws + (size_t)((b * H_ + h0) * S_) * D_;
  const float* kb = k_ws + (size_t)((b * H_ + h0) * S_ + i0) * D_;
  const float* vb = v_ws + (size_t)((b * H_ + h0) * S_) * D_;
  const float* rb = rpe + ((size_t)b * S_ + i0) * S_ * D_;

  // K fragments (constant indices only): kf[hh][ii] = 32B chunk dq of row
  float4 kf[HC][TI][2];
  #pragma unroll
  for (int hh = 0; hh < HC; ++hh)
    #pragma unroll
    for (int ii = 0; ii < TI; ++ii) {
      kf[hh][ii][0] = *reinterpret_cast<const float4*>(kb + hh * HS + ii * D_ + dq * 8);
      kf[hh][ii][1] = *reinterpret_cast<const float4*>(kb + hh * HS + ii * D_ + dq * 8 + 4);
    }

  // ---- scores: wave w covers j in {w*16 + pass*64 + j4} ----
  for (int jb = w * 16; jb < station; jb += 64) {
    const int j  = jb + j4;
    const int jc = j < S_ ? j : S_ - 1;
    float4 q[HC][2];
    #pragma unroll
    for (int hh = 0; hh < HC; ++hh) {
      q[hh][0] = *reinterpret_cast<const float4*>(qb + hh * HS + jc * D_ + dq * 8);
      q[hh][1] = *reinterpret_cast<const float4*>(qb + hh * HS + jc * D_ + dq * 8 + 4);
    }
    float4 rv[TI][2];
    #pragma unroll
    for (int ii = 0; ii < TI; ++ii) {
      rv[ii][0] = *reinterpret_cast<const float4*>(rb + ii * HS + jc * D_ + dq * 8);
      rv[ii][1] = *reinterpret_cast<const float4*>(rb + ii * HS + jc * D_ + dq * 8 + 4);
    }
    #pragma unroll
    for (int hh = 0; hh < HC; ++hh)
      #pragma unroll
      for (int ii = 0; ii < TI; ++ii) {
        float s = q[hh][0].x * kf[hh][ii][0].x * rv[ii][0].x;
        s = fmaf(q[hh][0].y * kf[hh][ii][0].y, rv[ii][0].y, s);
        s = fmaf(q[hh][0].z * kf[hh][ii][0].z, rv[ii][0].z, s);
        s = fmaf(q[hh][0].w * kf[hh][ii][0].w, rv[ii][0].w, s);
        s = fmaf(q[hh][1].x * kf[hh][ii][1].x, rv[ii][1].x, s);
        s = fmaf(q[hh][1].y * kf[hh][ii][1].y, rv[ii][1].y, s);
        s = fmaf(q[hh][1].z * kf[hh][ii][1].z, rv[ii][1].z, s);
        s = fmaf(q[hh][1].w * kf[hh][ii][1].w, rv[ii][1].w, s);
        s = red4(s);
        if (dq == 0 && j < station) p_smem[(hh * TI + ii) * S_ + j] = s;
      }
  }
  // diag cells beyond station (wave 0, lanes j4 < TI; cell ii=j4).
  // K loaded from global here (runtime row index) - no dynamic reg indexing.
  if (w == 0 && j4 < TI) {
    const int j = i0 + j4;
    if (j >= station) {
      const float4 r0 = *reinterpret_cast<const float4*>(rb + j4 * HS + j * D_ + dq * 8);
      const float4 r1 = *reinterpret_cast<const float4*>(rb + j4 * HS + j * D_ + dq * 8 + 4);
      #pragma unroll
      for (int hh = 0; hh < HC; ++hh) {
        const float4 q0 = *reinterpret_cast<const float4*>(qb + hh * HS + j * D_ + dq * 8);
        const float4 q1 = *reinterpret_cast<const float4*>(qb + hh * HS + j * D_ + dq * 8 + 4);
        const float4 k0 = *reinterpret_cast<const float4*>(kb + hh * HS + j4 * D_ + dq * 8);
        const float4 k1 = *reinterpret_cast<const float4*>(kb + hh * HS + j4 * D_ + dq * 8 + 4);
        float s = q0.x * k0.x * r0.x;
        s = fmaf(q0.y * k0.y, r0.y, s);
        s = fmaf(q0.z * k0.z, r0.z, s);
        s = fmaf(q0.w * k0.w, r0.w, s);
        s = fmaf(q1.x * k1.x, r1.x, s);
        s = fmaf(q1.y * k1.y, r1.y, s);
        s = fmaf(q1.z * k1.z, r1.z, s);
        s = fmaf(q1.w * k1.w, r1.w, s);
        s = red4(s);
        if (dq == 0) p_smem[(hh * TI + j4) * S_ + j] = s;
      }
    }
  }
  __syncthreads();

  // ---- softmax: wave w handles p-row w (NR == 4 rows) ----
  {
    const int r  = w;
    const int ii = r & (TI - 1);
    const int ig = i0 + ii;
    const bool dx = (ig >= station);
    float m = -1e30f;
    for (int jj = lane; jj < station; jj += 64) m = fmaxf(m, p_smem[r * S_ + jj]);
    const float dv = dx ? p_smem[r * S_ + ig] : -1e30f;
    m = fmaxf(m, dv);
    #pragma unroll
    for (int o = 32; o; o >>= 1) m = fmaxf(m, __shfl_xor(m, o, 64));
    float sum = 0.f;
    for (int jj = lane; jj < station; jj += 64) {
      const float e = __expf(p_smem[r * S_ + jj] - m);
      p_smem[r * S_ + jj] = e;
      sum += e;
    }
    #pragma unroll
    for (int o = 32; o; o >>= 1) sum += __shfl_xor(sum, o, 64);
    if (dx) {
      const float e = __expf(dv - m);
      sum += e;
      if (lane == 0) p_smem[r * S_ + ig] = e;
    }
    if (lane == 0) sums[r] = sum;
  }
  __syncthreads();

  // ---- attn @ V: thread (j8,dc) accumulates its j-slice, both heads ----
  float4 acc[HC][TI];
  #pragma unroll
  for (int hh = 0; hh < HC; ++hh)
    #pragma unroll
    for (int ii = 0; ii < TI; ++ii) acc[hh][ii] = make_float4(0.f, 0.f, 0.f, 0.f);

  for (int jb = w * 8; jb < station; jb += 32) {
    const int j  = jb + j8;
    const int jc = j < S_ ? j : S_ - 1;
    float4 v4[HC];
    #pragma unroll
    for (int hh = 0; hh < HC; ++hh)
      v4[hh] = *reinterpret_cast<const float4*>(vb + hh * HS + jc * D_ + dc * 4);
    #pragma unroll
    for (int hh = 0; hh < HC; ++hh)
      #pragma unroll
      for (int ii = 0; ii < TI; ++ii) {
        float pv = 0.f;
        if (j < station) pv = p_smem[(hh * TI + ii) * S_ + j];
        acc[hh][ii].x = fmaf(pv, v4[hh].x, acc[hh][ii].x);
        acc[hh][ii].y = fmaf(pv, v4[hh].y, acc[hh][ii].y);
        acc[hh][ii].z = fmaf(pv, v4[hh].z, acc[hh][ii].z);
        acc[hh][ii].w = fmaf(pv, v4[hh].w, acc[hh][ii].w);
      }
  }
  // diag contributions (exactly once: wave 0, j8==0 lanes)
  if (w == 0 && j8 == 0) {
    #pragma unroll
    for (int ii = 0; ii < TI; ++ii) {
      const int ig = i0 + ii;
      if (ig >= station) {
        #pragma unroll
        for (int hh = 0; hh < HC; ++hh) {
          const float pv = p_smem[(hh * TI + ii) * S_ + ig];
          const float4 v4 = *reinterpret_cast<const float4*>(vb + hh * HS + ig * D_ + dc * 4);
          acc[hh][ii].x = fmaf(pv, v4.x, acc[hh][ii].x);
          acc[hh][ii].y = fmaf(pv, v4.y, acc[hh][ii].y);
          acc[hh][ii].z = fmaf(pv, v4.z, acc[hh][ii].z);
          acc[hh][ii].w = fmaf(pv, v4.w, acc[hh][ii].w);
        }
      }
    }
  }
  __syncthreads();   // p_smem reads done before reuse as redv

  // ---- reduce over (w, j8): shfl pair-sum then LDS tree (reuse p_smem) ----
  // 16 groups (w, j8/2) x NR rows x 8 dc x float4 = 8 KB
  float4* redv = reinterpret_cast<float4*>(p_smem);
  #pragma unroll
  for (int hh = 0; hh < HC; ++hh)
    #pragma unroll
    for (int ii = 0; ii < TI; ++ii) {
      const int r = hh * TI + ii;
      float4 a = acc[hh][ii];
      a.x += __shfl_xor(a.x, 8);
      a.y += __shfl_xor(a.y, 8);
      a.z += __shfl_xor(a.z, 8);
      a.w += __shfl_xor(a.w, 8);
      if ((j8 & 1) == 0)
        redv[((w * 4 + (j8 >> 1)) * NR + r) * 8 + dc] = a;
    }
  __syncthreads();
  if (tid < NR * 8) {
    const int r = tid >> 3, d4 = tid & 7;
    float4 a = make_float4(0.f, 0.f, 0.f, 0.f);
    #pragma unroll
    for (int g = 0; g < 16; ++g) {
      const float4 x = redv[(g * NR + r) * 8 + d4];
      a.x += x.x; a.y += x.y; a.z += x.z; a.w += x.w;
    }
    const float inv = 1.f / sums[r];
    a.x *= inv; a.y *= inv; a.z *= inv; a.w *= inv;
    const int hh = r >> 1, ii = r & 1;             // TI == 2
    reinterpret_cast<float4*>(
        o_ws + (size_t)((b * H_ + h0 + hh) * S_ + i0 + ii) * D_)[d4] = a;
  }
}

// ---------------------------------------------------------------------------
// Kernel C: ctx = O @ fc_w + fc_b + hidden, then LayerNorm.
// grid = B*S/NROW, block = 256 (thread per output column m).
// ---------------------------------------------------------------------------
__global__ __launch_bounds__(256) void fc_ln_kernel(
    const float* __restrict__ o_ws, const float* __restrict__ fc_w,
    const float* __restrict__ fc_b, const float* __restrict__ hid,
    const float* __restrict__ ln_w, const float* __restrict__ ln_b,
    float* __restrict__ out)
{
  __shared__ float orow[NROW][HD_];
  __shared__ float red[NROW][4];
  const int tid = threadIdx.x;
  const int r0 = blockIdx.x * NROW;

  for (int idx = tid; idx < NROW * HD_; idx += 256) {
    const int r = idx >> 8, m = idx & 255;
    const int g = r0 + r;
    const int b = g >> 9, i = g & (S_ - 1);
    orow[r][m] = o_ws[((b * H_ + (m >> 5)) * S_ + i) * D_ + (m & 31)];
  }
  __syncthreads();

  float acc[NROW] = {0.f, 0.f, 0.f, 0.f};
  const float* wp = fc_w + tid;
  #pragma unroll 8
  for (int n4 = 0; n4 < HD_ / 4; ++n4) {
    const float w0 = wp[(4 * n4 + 0) * DM_];
    const float w1 = wp[(4 * n4 + 1) * DM_];
    const float w2 = wp[(4 * n4 + 2) * DM_];
    const float w3 = wp[(4 * n4 + 3) * DM_];
    #pragma unroll
    for (int r = 0; r < NROW; ++r) {
      const float4 ov = reinterpret_cast<const float4*>(&orow[r][0])[n4];
      acc[r] = fmaf(ov.x, w0, acc[r]);
      acc[r] = fmaf(ov.y, w1, acc[r]);
      acc[r] = fmaf(ov.z, w2, acc[r]);
      acc[r] = fmaf(ov.w, w3, acc[r]);
    }
  }
  const float bias = fc_b[tid];
  #pragma unroll
  for (int r = 0; r < NROW; ++r) acc[r] += bias + hid[(r0 + r) * DM_ + tid];

  // ---- LayerNorm over DM per row ----
  const int w = tid >> 6, lane = tid & 63;
  float mu[NROW];
  #pragma unroll
  for (int r = 0; r < NROW; ++r) {
    float s = acc[r];
    #pragma unroll
    for (int o = 32; o; o >>= 1) s += __shfl_xor(s, o, 64);
    if (lane == 0) red[r][w] = s;
  }
  __syncthreads();
  #pragma unroll
  for (int r = 0; r < NROW; ++r)
    mu[r] = (red[r][0] + red[r][1] + red[r][2] + red[r][3]) * (1.f / DM_);
  __syncthreads();
  #pragma unroll
  for (int r = 0; r < NROW; ++r) {
    const float dd = acc[r] - mu[r];
    float s = dd * dd;
    #pragma unroll
    for (int o = 32; o; o >>= 1) s += __shfl_xor(s, o, 64);
    if (lane == 0) red[r][w] = s;
  }
  __syncthreads();
  const float lw = ln_w[tid], lb = ln_b[tid];
  #pragma unroll
  for (int r = 0; r < NROW; ++r) {
    const float var = (red[r][0] + red[r][1] + red[r][2] + red[r][3]) * (1.f / DM_);
    out[(r0 + r) * DM_ + tid] =
        (acc[r] - mu[r]) * rsqrtf(var + 1e-6f) * lw + lb;
  }
}

// ---------------------------------------------------------------------------
extern "C" void kernel_launch(void* const* d_in, const int* in_sizes, int n_in,
                              void* d_out, int out_size, void* d_ws, size_t ws_size,
                              hipStream_t stream) {
  const float* hid = (const float*)d_in[0];
  const float* rpe = (const float*)d_in[1];
  const float* wq  = (const float*)d_in[2];
  const float* wk  = (const float*)d_in[3];
  const float* wv  = (const float*)d_in[4];
  const float* fcw = (const float*)d_in[5];
  const float* fcb = (const float*)d_in[6];
  const float* lnw = (const float*)d_in[7];
  const float* lnb = (const float*)d_in[8];
  const int* station = (const int*)d_in[9];
  float* out = (float*)d_out;

  const size_t per = (size_t)B_ * H_ * S_ * D_;   // 262144 floats
  float* q_ws = (float*)d_ws;
  float* k_ws = q_ws + per;
  float* v_ws = k_ws + per;
  float* o_ws = v_ws + per;

  dim3 gA(B_ * S_ / NROW, 3);
  qkv_kernel<<<gA, 256, 0, stream>>>(hid, wq, wk, wv, q_ws, k_ws, v_ws);
  attn_kernel<<<B_ * (S_ / TI) * (H_ / HC), 256, 0, stream>>>(
      rpe, q_ws, k_ws, v_ws, station, o_ws);
  fc_ln_kernel<<<B_ * S_ / NROW, 256, 0, stream>>>(o_ws, fcw, fcb, hid, lnw, lnb, out);
}